// Round 3
// baseline (166.879 us; speedup 1.0000x reference)
//
#include <hip/hip_runtime.h>

#define N 8192
#define D 128
#define MARGIN 0.5f
#define FLT_BIG 3.402823466e+38f

typedef __bf16 bf16x8 __attribute__((ext_vector_type(8)));
typedef float f32x4 __attribute__((ext_vector_type(4)));

__device__ __forceinline__ unsigned short f2bf_rne(float f) {
  unsigned u = __float_as_uint(f);
  u += 0x7FFFu + ((u >> 16) & 1u);  // round-to-nearest-even (inputs finite)
  return (unsigned short)(u >> 16);
}

// ---------------- K1: fp32->bf16 + row norms + all init (+ hist in block 0) ----
__global__ void k_prep(const float* __restrict__ x, const int* __restrict__ lab,
                       unsigned short* __restrict__ xb, float* __restrict__ sq,
                       unsigned* __restrict__ posw, unsigned* __restrict__ negw,
                       unsigned* __restrict__ hist, float* __restrict__ acc,
                       unsigned* __restrict__ ticket) {
  const int t = threadIdx.x;
  const int row = blockIdx.x * 8 + (t >> 5);
  const int l32 = t & 31;
  const float4 v = ((const float4*)x)[row * 32 + l32];
  ushort4 o;
  o.x = f2bf_rne(v.x); o.y = f2bf_rne(v.y);
  o.z = f2bf_rne(v.z); o.w = f2bf_rne(v.w);
  ((ushort4*)xb)[row * 32 + l32] = o;
  float s = v.x * v.x + v.y * v.y + v.z * v.z + v.w * v.w;
#pragma unroll
  for (int off = 1; off < 32; off <<= 1) s += __shfl_xor(s, off, 64);
  if (l32 == 0) {
    sq[row] = s;
    posw[row] = 0u;           // max(d2) accumulator
    negw[row] = 0x7F800000u;  // min(d2) accumulator = +inf
  }

  if (blockIdx.x == 0) {  // label histogram
    __shared__ unsigned h[8];
    if (t < 8) h[t] = 0u;
    __syncthreads();
    unsigned long long cA = 0ull, cB = 0ull;  // 4x16-bit packed counters each
#pragma unroll
    for (int it = 0; it < 32; ++it) {
      const int l = lab[t + it * 256] & 7;
      if (l < 4) cA += 1ull << (l * 16);
      else       cB += 1ull << ((l - 4) * 16);
    }
#pragma unroll
    for (int off = 1; off < 64; off <<= 1) {
      cA += __shfl_xor(cA, off, 64);
      cB += __shfl_xor(cB, off, 64);
    }
    if ((t & 63) == 0) {
#pragma unroll
      for (int q = 0; q < 4; ++q) {
        atomicAdd(&h[q],     (unsigned)((cA >> (q * 16)) & 0xFFFFu));
        atomicAdd(&h[4 + q], (unsigned)((cB >> (q * 16)) & 0xFFFFu));
      }
    }
    __syncthreads();
    if (t < 8) hist[t] = h[t];
    if (t == 0) { acc[0] = 0.f; acc[1] = 0.f; ticket[0] = 0u; }
  }
}

// ---------------- K2: fused GEMM + hardest-pos/neg mining ----------------
// grid (64,16) x 256thr. Block: 128 i x 512 j; 16 double-buffered 32-row tiles.
// Staging: async global_load_lds (16B), XOR swizzle folded into SOURCE address
// (LDS dest must be contiguous lane*16). One barrier per tile; prefetch t+1
// issued before compute of t so the barrier's vmcnt drain is nearly free.
__global__ __launch_bounds__(256, 5) void k_mine(
    const unsigned short* __restrict__ xb, const float* __restrict__ sq,
    const int* __restrict__ lab, unsigned* __restrict__ posw, unsigned* __restrict__ negw) {
  __shared__ __align__(16) unsigned short lds_b[2][32 * 128];  // 2 x 8 KB

  const int t = threadIdx.x;
  const int w = t >> 6;
  const int lane = t & 63;
  const int col = lane & 15;   // MFMA m/n selector
  const int quad = lane >> 4;  // MFMA k-group / C row group
  const int iblk = blockIdx.x * 128;
  const int i0 = iblk + w * 32;
  const int jbase = blockIdx.y * 512;

  // per-lane source offsets for the 2 staging segments this lane serves:
  // segment s = p*4 + w covers tile rows 4s..4s+3; lane -> row 4s+(lane>>4),
  // chunk slot c = lane&15 holds global chunk c ^ (row&7).
  int srow[2], schunk[2];
#pragma unroll
  for (int p = 0; p < 2; ++p) {
    const int s = p * 4 + w;
    srow[p] = s * 4 + (lane >> 4);
    schunk[p] = (lane & 15) ^ (srow[p] & 7);
  }

#define PREFETCH(J0, BUF)                                                      \
  {                                                                            \
    _Pragma("unroll")                                                          \
    for (int p = 0; p < 2; ++p) {                                              \
      const unsigned short* g = xb + (size_t)((J0) + srow[p]) * D + schunk[p] * 8; \
      __builtin_amdgcn_global_load_lds(                                        \
          (const __attribute__((address_space(1))) void*)g,                    \
          (__attribute__((address_space(3))) void*)(&lds_b[(BUF)][(p * 4 + w) * 512]), \
          16, 0, 0);                                                           \
    }                                                                          \
  }

  // A fragments resident: 2 i-subtiles x 4 k-steps
  bf16x8 a[2][4];
#pragma unroll
  for (int is = 0; is < 2; ++is) {
    const unsigned short* arow = xb + (size_t)(i0 + is * 16 + col) * D + quad * 8;
#pragma unroll
    for (int k = 0; k < 4; ++k) a[is][k] = *(const bf16x8*)(arow + k * 32);
  }

  int labi[2][4];
#pragma unroll
  for (int is = 0; is < 2; ++is)
#pragma unroll
    for (int r = 0; r < 4; ++r) labi[is][r] = lab[i0 + is * 16 + quad * 4 + r];

  float pos[2][4], neg[2][4];
#pragma unroll
  for (int is = 0; is < 2; ++is)
#pragma unroll
    for (int r = 0; r < 4; ++r) { pos[is][r] = -FLT_BIG; neg[is][r] = FLT_BIG; }

  // swizzled LDS read offsets (bytes within a tile buffer), k-indexed
  const int cm = col & 7;
  int coff[4];
#pragma unroll
  for (int k = 0; k < 4; ++k) coff[k] = col * 256 + (((k * 4 + quad) ^ cm) * 16);

  // prefetch tile 0 + its sq/lab into registers
  PREFETCH(jbase, 0);
  float sqc[2];
  int labc[2];
#pragma unroll
  for (int s = 0; s < 2; ++s) {
    sqc[s] = sq[jbase + s * 16 + col];
    labc[s] = lab[jbase + s * 16 + col];
  }
  __syncthreads();  // drains vmcnt(0): tile 0 + A frags landed

#pragma unroll
  for (int jt = 0; jt < 16; ++jt) {
    const int cur = jt & 1;
    const int j0 = jbase + jt * 32;
    float sqn[2];
    int labn[2];
    if (jt < 15) {  // issue next-tile prefetch first: in flight during compute
      PREFETCH(j0 + 32, cur ^ 1);
#pragma unroll
      for (int s = 0; s < 2; ++s) {
        sqn[s] = sq[j0 + 32 + s * 16 + col];
        labn[s] = lab[j0 + 32 + s * 16 + col];
      }
    }
    const bool diag = (j0 < iblk + 128) && (iblk < j0 + 32);

#pragma unroll
    for (int s = 0; s < 2; ++s) {
      f32x4 acc0 = {0.f, 0.f, 0.f, 0.f}, acc1 = {0.f, 0.f, 0.f, 0.f};
#pragma unroll
      for (int k = 0; k < 4; ++k) {
        const bf16x8 b = *(const bf16x8*)((const char*)&lds_b[cur][0] + s * 4096 + coff[k]);
        acc0 = __builtin_amdgcn_mfma_f32_16x16x32_bf16(a[0][k], b, acc0, 0, 0, 0);
        acc1 = __builtin_amdgcn_mfma_f32_16x16x32_bf16(a[1][k], b, acc1, 0, 0, 0);
      }
      const float sqj = sqc[s];
      const int labj = labc[s];
      if (!diag) {
#pragma unroll
        for (int r = 0; r < 4; ++r) {
          const float m0 = fmaf(-2.f, acc0[r], sqj);
          const float m1 = fmaf(-2.f, acc1[r], sqj);
          const bool s0 = (labi[0][r] == labj);
          const bool s1 = (labi[1][r] == labj);
          pos[0][r] = fmaxf(pos[0][r], s0 ? m0 : -FLT_BIG);
          neg[0][r] = fminf(neg[0][r], s0 ? FLT_BIG : m0);
          pos[1][r] = fmaxf(pos[1][r], s1 ? m1 : -FLT_BIG);
          neg[1][r] = fminf(neg[1][r], s1 ? FLT_BIG : m1);
        }
      } else {
        const int jg = j0 + s * 16 + col;
#pragma unroll
        for (int r = 0; r < 4; ++r) {
          const int ir = quad * 4 + r;
          const float m0 = fmaf(-2.f, acc0[r], sqj);
          const float m1 = fmaf(-2.f, acc1[r], sqj);
          const bool s0 = (labi[0][r] == labj) && (jg != i0 + ir);
          const bool s1 = (labi[1][r] == labj) && (jg != i0 + 16 + ir);
          pos[0][r] = fmaxf(pos[0][r], s0 ? m0 : -FLT_BIG);
          neg[0][r] = fminf(neg[0][r], (labi[0][r] == labj) ? FLT_BIG : m0);
          pos[1][r] = fmaxf(pos[1][r], s1 ? m1 : -FLT_BIG);
          neg[1][r] = fminf(neg[1][r], (labi[1][r] == labj) ? FLT_BIG : m1);
        }
      }
    }
    if (jt < 15) {
#pragma unroll
      for (int s = 0; s < 2; ++s) { sqc[s] = sqn[s]; labc[s] = labn[s]; }
      __syncthreads();  // drains next-tile prefetch (issued ~compute-length ago) + guards buf reuse
    }
  }

  // reduce the 16 cols sharing each i-row, add sq_i back, combine via atomics
#pragma unroll
  for (int is = 0; is < 2; ++is)
#pragma unroll
    for (int r = 0; r < 4; ++r) {
      float p = pos[is][r], n = neg[is][r];
#pragma unroll
      for (int off = 1; off < 16; off <<= 1) {
        p = fmaxf(p, __shfl_xor(p, off, 64));
        n = fminf(n, __shfl_xor(n, off, 64));
      }
      if (col == 0) {
        const int i = i0 + is * 16 + quad * 4 + r;
        const float sqi = sq[i];
        atomicMax(posw + i, __float_as_uint(fmaxf(sqi + p, 0.f)));
        atomicMin(negw + i, __float_as_uint(fmaxf(sqi + n, 0.f)));
      }
    }
#undef PREFETCH
}

// ---------------- K3: per-row loss + global reduce + finalize (ticketed) -----
__global__ void k_tail(const unsigned* __restrict__ posw, const unsigned* __restrict__ negw,
                       const int* __restrict__ lab, const unsigned* __restrict__ hist,
                       float* __restrict__ acc, unsigned* __restrict__ ticket,
                       float* __restrict__ out) {
  __shared__ float ls[4], cs[4];
  const int t = threadIdx.x;
  const int i = blockIdx.x * 256 + t;
  const float pd2 = __uint_as_float(posw[i]);
  const float nd2 = __uint_as_float(negw[i]);
  const unsigned cnt = hist[lab[i] & 7];
  const bool valid = (cnt >= 2u) && (cnt < (unsigned)N);
  float loss = 0.f, c = 0.f;
  if (valid) {
    loss = fmaxf(sqrtf(pd2) - sqrtf(fminf(nd2, FLT_BIG)) + MARGIN, 0.f);
    c = 1.f;
  }
#pragma unroll
  for (int off = 1; off < 64; off <<= 1) {
    loss += __shfl_xor(loss, off, 64);
    c += __shfl_xor(c, off, 64);
  }
  const int wv = t >> 6;
  if ((t & 63) == 0) { ls[wv] = loss; cs[wv] = c; }
  __syncthreads();
  if (t == 0) {
    atomicAdd(acc + 0, ls[0] + ls[1] + ls[2] + ls[3]);
    atomicAdd(acc + 1, cs[0] + cs[1] + cs[2] + cs[3]);
    __threadfence();
    const unsigned tk = atomicAdd(ticket, 1u);
    if (tk == 31u) {  // last block: partials fenced-in; read via atomics (coherent)
      const float lsum = atomicAdd(acc + 0, 0.f);
      const float csum = atomicAdd(acc + 1, 0.f);
      out[0] = lsum / fmaxf(csum, 1.f);
    }
  }
}

extern "C" void kernel_launch(void* const* d_in, const int* in_sizes, int n_in,
                              void* d_out, int out_size, void* d_ws, size_t ws_size,
                              hipStream_t stream) {
  const float* x = (const float*)d_in[0];
  const int* lab = (const int*)d_in[1];
  char* ws = (char*)d_ws;
  unsigned short* xb = (unsigned short*)ws;                 // 2 MB bf16 copy
  float* sq = (float*)(ws + (size_t)N * D * 2);             // 32 KB
  unsigned* posw = (unsigned*)((char*)sq + (size_t)N * 4);  // 32 KB
  unsigned* negw = posw + N;                                // 32 KB
  unsigned* hist = negw + N;                                // 32 B
  unsigned* ticket = hist + 8;                              // 4 B
  float* acc = (float*)(ticket + 1);                        // 8 B
  float* out = (float*)d_out;

  hipLaunchKernelGGL(k_prep, dim3(1024), dim3(256), 0, stream, x, lab, xb, sq,
                     posw, negw, hist, acc, ticket);
  hipLaunchKernelGGL(k_mine, dim3(64, 16), dim3(256), 0, stream, xb, sq, lab, posw, negw);
  hipLaunchKernelGGL(k_tail, dim3(32), dim3(256), 0, stream, posw, negw, lab, hist,
                     acc, ticket, out);
}

// Round 4
// 106.376 us; speedup vs baseline: 1.5688x; 1.5688x over previous
//
#include <hip/hip_runtime.h>

#define N 8192
#define D 128
#define MARGIN 0.5f
#define FLT_BIG 3.402823466e+38f

typedef __bf16 bf16x8 __attribute__((ext_vector_type(8)));
typedef float f32x4 __attribute__((ext_vector_type(4)));

__device__ __forceinline__ unsigned short f2bf_rne(float f) {
  unsigned u = __float_as_uint(f);
  u += 0x7FFFu + ((u >> 16) & 1u);  // round-to-nearest-even (inputs finite)
  return (unsigned short)(u >> 16);
}

// ---------------- K1: fp32->bf16 + row norms + all init (+ hist in block 0) ----
__global__ void k_prep(const float* __restrict__ x, const int* __restrict__ lab,
                       unsigned short* __restrict__ xb, float* __restrict__ sq,
                       unsigned* __restrict__ posw, unsigned* __restrict__ negw,
                       unsigned* __restrict__ hist, float* __restrict__ acc,
                       unsigned* __restrict__ ticket) {
  const int t = threadIdx.x;
  const int row = blockIdx.x * 8 + (t >> 5);
  const int l32 = t & 31;
  const float4 v = ((const float4*)x)[row * 32 + l32];
  ushort4 o;
  o.x = f2bf_rne(v.x); o.y = f2bf_rne(v.y);
  o.z = f2bf_rne(v.z); o.w = f2bf_rne(v.w);
  ((ushort4*)xb)[row * 32 + l32] = o;
  float s = v.x * v.x + v.y * v.y + v.z * v.z + v.w * v.w;
#pragma unroll
  for (int off = 1; off < 32; off <<= 1) s += __shfl_xor(s, off, 64);
  if (l32 == 0) {
    sq[row] = s;
    posw[row] = 0u;           // max(d2) accumulator
    negw[row] = 0x7F800000u;  // min(d2) accumulator = +inf
  }

  if (blockIdx.x == 0) {  // label histogram
    __shared__ unsigned h[8];
    if (t < 8) h[t] = 0u;
    __syncthreads();
    unsigned long long cA = 0ull, cB = 0ull;  // 4x16-bit packed counters each
#pragma unroll
    for (int it = 0; it < 32; ++it) {
      const int l = lab[t + it * 256] & 7;
      if (l < 4) cA += 1ull << (l * 16);
      else       cB += 1ull << ((l - 4) * 16);
    }
#pragma unroll
    for (int off = 1; off < 64; off <<= 1) {
      cA += __shfl_xor(cA, off, 64);
      cB += __shfl_xor(cB, off, 64);
    }
    if ((t & 63) == 0) {
#pragma unroll
      for (int q = 0; q < 4; ++q) {
        atomicAdd(&h[q],     (unsigned)((cA >> (q * 16)) & 0xFFFFu));
        atomicAdd(&h[4 + q], (unsigned)((cB >> (q * 16)) & 0xFFFFu));
      }
    }
    __syncthreads();
    if (t < 8) hist[t] = h[t];
    if (t == 0) { acc[0] = 0.f; acc[1] = 0.f; ticket[0] = 0u; }
  }
}

// ---------------- K2: fused GEMM + hardest-pos/neg mining ----------------
// grid (64,32) x 256thr. Block: 128 i x 256 j; 8 double-buffered 32-row tiles.
// Async global_load_lds (16B) with XOR swizzle folded into the SOURCE address;
// one barrier per tile, prefetch t+1 issued before compute of t.
// sq/lab for the whole 256-j range staged to LDS once (no per-tile state).
__global__ __launch_bounds__(256, 4) void k_mine(
    const unsigned short* __restrict__ xb, const float* __restrict__ sq,
    const int* __restrict__ lab, unsigned* __restrict__ posw, unsigned* __restrict__ negw) {
  __shared__ __align__(16) unsigned short lds_b[2][32 * 128];  // 2 x 8 KB
  __shared__ float lds_sq[256];
  __shared__ int lds_lab[256];

  const int t = threadIdx.x;
  const int w = t >> 6;
  const int lane = t & 63;
  const int col = lane & 15;   // MFMA m/n selector
  const int quad = lane >> 4;  // MFMA k-group / C row group
  const int iblk = blockIdx.x * 128;
  const int i0 = iblk + w * 32;
  const int jbase = blockIdx.y * 256;

  // staging geometry: 8 segments of 4 rows; lane -> row 4s+(lane>>4),
  // slot c = lane&15 receives global chunk c ^ (row&7) (swizzle in source addr)
  int srow[2], schunk[2];
#pragma unroll
  for (int p = 0; p < 2; ++p) {
    const int s = p * 4 + w;
    srow[p] = s * 4 + (lane >> 4);
    schunk[p] = (lane & 15) ^ (srow[p] & 7);
  }

#define PREFETCH(J0, BUF)                                                      \
  {                                                                            \
    _Pragma("unroll")                                                          \
    for (int p = 0; p < 2; ++p) {                                              \
      const unsigned short* g = xb + (size_t)((J0) + srow[p]) * D + schunk[p] * 8; \
      __builtin_amdgcn_global_load_lds(                                        \
          (const __attribute__((address_space(1))) void*)g,                    \
          (__attribute__((address_space(3))) void*)(&lds_b[(BUF)][(p * 4 + w) * 512]), \
          16, 0, 0);                                                           \
    }                                                                          \
  }

  // stage sq/lab for the block's whole j-range (read-only for the whole loop)
  lds_sq[t] = sq[jbase + t];
  lds_lab[t] = lab[jbase + t];

  PREFETCH(jbase, 0);

  // A fragments resident: 2 i-subtiles x 4 k-steps
  bf16x8 a[2][4];
#pragma unroll
  for (int is = 0; is < 2; ++is) {
    const unsigned short* arow = xb + (size_t)(i0 + is * 16 + col) * D + quad * 8;
#pragma unroll
    for (int k = 0; k < 4; ++k) a[is][k] = *(const bf16x8*)(arow + k * 32);
  }

  int labi[2][4];
#pragma unroll
  for (int is = 0; is < 2; ++is)
#pragma unroll
    for (int r = 0; r < 4; ++r) labi[is][r] = lab[i0 + is * 16 + quad * 4 + r];

  float pos[2][4], neg[2][4];
#pragma unroll
  for (int is = 0; is < 2; ++is)
#pragma unroll
    for (int r = 0; r < 4; ++r) { pos[is][r] = -FLT_BIG; neg[is][r] = FLT_BIG; }

  // swizzled LDS read offsets (bytes within a tile buffer), k-indexed
  const int cm = col & 7;
  int coff[4];
#pragma unroll
  for (int k = 0; k < 4; ++k) coff[k] = col * 256 + (((k * 4 + quad) ^ cm) * 16);

  __syncthreads();  // tile 0 + sq/lab staged

#define PROC(TT, BUF)                                                          \
  {                                                                            \
    const int tt = (TT);                                                       \
    const int j0 = jbase + tt * 32;                                            \
    if (tt < 7) PREFETCH(j0 + 32, (BUF) ^ 1);                                  \
    const bool diag = (j0 < iblk + 128) && (iblk < j0 + 32);                   \
    _Pragma("unroll")                                                          \
    for (int s = 0; s < 2; ++s) {                                              \
      f32x4 acc0 = {0.f, 0.f, 0.f, 0.f}, acc1 = {0.f, 0.f, 0.f, 0.f};          \
      _Pragma("unroll")                                                        \
      for (int k = 0; k < 4; ++k) {                                            \
        const bf16x8 b =                                                       \
            *(const bf16x8*)((const char*)&lds_b[(BUF)][0] + s * 4096 + coff[k]); \
        acc0 = __builtin_amdgcn_mfma_f32_16x16x32_bf16(a[0][k], b, acc0, 0, 0, 0); \
        acc1 = __builtin_amdgcn_mfma_f32_16x16x32_bf16(a[1][k], b, acc1, 0, 0, 0); \
      }                                                                        \
      const int jc = tt * 32 + s * 16 + col;                                   \
      const float sqj = lds_sq[jc];                                            \
      const int labj = lds_lab[jc];                                            \
      if (!diag) {                                                             \
        _Pragma("unroll")                                                      \
        for (int r = 0; r < 4; ++r) {                                          \
          const float m0 = fmaf(-2.f, acc0[r], sqj);                           \
          const float m1 = fmaf(-2.f, acc1[r], sqj);                           \
          const bool s0 = (labi[0][r] == labj);                                \
          const bool s1 = (labi[1][r] == labj);                                \
          pos[0][r] = fmaxf(pos[0][r], s0 ? m0 : -FLT_BIG);                    \
          neg[0][r] = fminf(neg[0][r], s0 ? FLT_BIG : m0);                     \
          pos[1][r] = fmaxf(pos[1][r], s1 ? m1 : -FLT_BIG);                    \
          neg[1][r] = fminf(neg[1][r], s1 ? FLT_BIG : m1);                     \
        }                                                                      \
      } else {                                                                 \
        const int jg = jbase + jc;                                             \
        _Pragma("unroll")                                                      \
        for (int r = 0; r < 4; ++r) {                                          \
          const int ir = quad * 4 + r;                                         \
          const float m0 = fmaf(-2.f, acc0[r], sqj);                           \
          const float m1 = fmaf(-2.f, acc1[r], sqj);                           \
          const bool s0 = (labi[0][r] == labj) && (jg != i0 + ir);             \
          const bool s1 = (labi[1][r] == labj) && (jg != i0 + 16 + ir);        \
          pos[0][r] = fmaxf(pos[0][r], s0 ? m0 : -FLT_BIG);                    \
          neg[0][r] = fminf(neg[0][r], (labi[0][r] == labj) ? FLT_BIG : m0);   \
          pos[1][r] = fmaxf(pos[1][r], s1 ? m1 : -FLT_BIG);                    \
          neg[1][r] = fminf(neg[1][r], (labi[1][r] == labj) ? FLT_BIG : m1);   \
        }                                                                      \
      }                                                                        \
    }                                                                          \
    if (tt < 7) __syncthreads(); /* next tile landed + guards buf reuse */     \
  }

  for (int jp = 0; jp < 4; ++jp) {
    PROC(jp * 2, 0);
    PROC(jp * 2 + 1, 1);
  }

  // reduce the 16 cols sharing each i-row, add sq_i back, combine via atomics
#pragma unroll
  for (int is = 0; is < 2; ++is)
#pragma unroll
    for (int r = 0; r < 4; ++r) {
      float p = pos[is][r], n = neg[is][r];
#pragma unroll
      for (int off = 1; off < 16; off <<= 1) {
        p = fmaxf(p, __shfl_xor(p, off, 64));
        n = fminf(n, __shfl_xor(n, off, 64));
      }
      if (col == 0) {
        const int i = i0 + is * 16 + quad * 4 + r;
        const float sqi = sq[i];
        atomicMax(posw + i, __float_as_uint(fmaxf(sqi + p, 0.f)));
        atomicMin(negw + i, __float_as_uint(fmaxf(sqi + n, 0.f)));
      }
    }
#undef PROC
#undef PREFETCH
}

// ---------------- K3: per-row loss + global reduce + finalize (ticketed) -----
__global__ void k_tail(const unsigned* __restrict__ posw, const unsigned* __restrict__ negw,
                       const int* __restrict__ lab, const unsigned* __restrict__ hist,
                       float* __restrict__ acc, unsigned* __restrict__ ticket,
                       float* __restrict__ out) {
  __shared__ float ls[4], cs[4];
  const int t = threadIdx.x;
  const int i = blockIdx.x * 256 + t;
  const float pd2 = __uint_as_float(posw[i]);
  const float nd2 = __uint_as_float(negw[i]);
  const unsigned cnt = hist[lab[i] & 7];
  const bool valid = (cnt >= 2u) && (cnt < (unsigned)N);
  float loss = 0.f, c = 0.f;
  if (valid) {
    loss = fmaxf(sqrtf(pd2) - sqrtf(fminf(nd2, FLT_BIG)) + MARGIN, 0.f);
    c = 1.f;
  }
#pragma unroll
  for (int off = 1; off < 64; off <<= 1) {
    loss += __shfl_xor(loss, off, 64);
    c += __shfl_xor(c, off, 64);
  }
  const int wv = t >> 6;
  if ((t & 63) == 0) { ls[wv] = loss; cs[wv] = c; }
  __syncthreads();
  if (t == 0) {
    atomicAdd(acc + 0, ls[0] + ls[1] + ls[2] + ls[3]);
    atomicAdd(acc + 1, cs[0] + cs[1] + cs[2] + cs[3]);
    __threadfence();
    const unsigned tk = atomicAdd(ticket, 1u);
    if (tk == 31u) {  // last block: partials fenced-in; read via atomics (coherent)
      const float lsum = atomicAdd(acc + 0, 0.f);
      const float csum = atomicAdd(acc + 1, 0.f);
      out[0] = lsum / fmaxf(csum, 1.f);
    }
  }
}

extern "C" void kernel_launch(void* const* d_in, const int* in_sizes, int n_in,
                              void* d_out, int out_size, void* d_ws, size_t ws_size,
                              hipStream_t stream) {
  const float* x = (const float*)d_in[0];
  const int* lab = (const int*)d_in[1];
  char* ws = (char*)d_ws;
  unsigned short* xb = (unsigned short*)ws;                 // 2 MB bf16 copy
  float* sq = (float*)(ws + (size_t)N * D * 2);             // 32 KB
  unsigned* posw = (unsigned*)((char*)sq + (size_t)N * 4);  // 32 KB
  unsigned* negw = posw + N;                                // 32 KB
  unsigned* hist = negw + N;                                // 32 B
  unsigned* ticket = hist + 8;                              // 4 B
  float* acc = (float*)(ticket + 1);                        // 8 B
  float* out = (float*)d_out;

  hipLaunchKernelGGL(k_prep, dim3(1024), dim3(256), 0, stream, x, lab, xb, sq,
                     posw, negw, hist, acc, ticket);
  hipLaunchKernelGGL(k_mine, dim3(64, 32), dim3(256), 0, stream, xb, sq, lab, posw, negw);
  hipLaunchKernelGGL(k_tail, dim3(32), dim3(256), 0, stream, posw, negw, lab, hist,
                     acc, ticket, out);
}